// Round 6
// baseline (676.453 us; speedup 1.0000x reference)
//
#include <hip/hip_runtime.h>
#include <math.h>

#define DDIM 1024

// ---- workspace layout (float offsets) ----
#define O_XPA   0          // [32][8][1024]  262144
#define O_VP    327680     // [16][8][1024]  131072
#define O_YP    458752     // [48][8][1024]  393216  (y0 | h0 | h1)
#define O_T0    851968     // [16][8][1024]  131072
#define O_A0    983040     // [16][8][1024]  131072
#define O_S0    1114112    // [16][8][1024]  131072
#define O_MP    1245184    // [16][8][1024]  131072
#define O_COMB  1376256    // [8][2048]       16384
#define O_HBA   1392640    // [32][8][2048]  524288
#define O_HBP   1916928    // [32][8][1024]  262144
#define O_ROW   2179072    // [8][1024]        8192
#define O_BAR   2187264    // barrier region: arrive[16][16][32] + release[256][32] ints

#define NBLK 256
#define NPH  16

struct P {
    const float *x, *w_v, *b_v, *w_o, *b_o, *aw1, *ab1, *aw2, *ab2, *vqc,
                *pw1, *pb1, *pw2, *pb2, *mew1, *meb1, *mew2, *meb2, *mst,
                *rw1, *rb1, *rw2, *rb2, *brw1, *brb1, *brw2, *brb2, *lnsc, *lnof;
    float *ws;
    float *out;
};

// ---- LLC-resident (write-through, L2-bypassing) accessors for inter-phase data ----
__device__ __forceinline__ float ldv(const float* p) {
    return __hip_atomic_load(p, __ATOMIC_RELAXED, __HIP_MEMORY_SCOPE_AGENT);
}
__device__ __forceinline__ void stv(float* p, float v) {
    __hip_atomic_store(p, v, __ATOMIC_RELAXED, __HIP_MEMORY_SCOPE_AGENT);
}

// ---- grid barrier: hierarchical arrival + per-block release flags ----
__device__ __forceinline__ void gbar(int* __restrict__ bar, int ph) {
    int blk = blockIdx.x, t = threadIdx.x;
    int* arrive  = bar;                   // NPH*16*32 ints
    int* release = bar + NPH * 16 * 32;   // NBLK*32 ints
    __syncthreads();
    if (t == 0)
        __hip_atomic_fetch_add(&arrive[(ph * 16 + (blk >> 4)) * 32], 1,
                               __ATOMIC_RELEASE, __HIP_MEMORY_SCOPE_AGENT);
    if (blk == 0) {
        if (t < 16) {
            int* cnt = &arrive[(ph * 16 + t) * 32];
            while (__hip_atomic_load(cnt, __ATOMIC_ACQUIRE, __HIP_MEMORY_SCOPE_AGENT) < 16)
                __builtin_amdgcn_s_sleep(2);
        }
        __syncthreads();
        __hip_atomic_store(&release[t * 32], ph + 1,
                           __ATOMIC_RELEASE, __HIP_MEMORY_SCOPE_AGENT);
    } else {
        if (t == 0) {
            while (__hip_atomic_load(&release[blk * 32], __ATOMIC_ACQUIRE,
                                     __HIP_MEMORY_SCOPE_AGENT) < ph + 1)
                __builtin_amdgcn_s_sleep(2);
        }
    }
    __syncthreads();
}

// Generic batch-8 vec-mat stage, 64x64 tiles, grid-stride. SINGLE code copy (noinline).
// in_parts: [NP][8][K] (summed at staging via LLC loads); out_part: [nKT][8][Dout] (LLC stores).
// act: 0=id 1=tanh 2=silu 3=*quantum-scale(vqc). Bias added on kt==0.
__device__ __attribute__((noinline)) void mv_stage(int blk, int t,
        const float* __restrict__ in_parts, int NP,
        const float* __restrict__ W, const float* __restrict__ bias,
        float* __restrict__ out_part, const float* __restrict__ vqc,
        float premul, int act, int K, int Dout, float* smem) {
    int nJT = Dout >> 6, nKT = K >> 6;
    int ntiles = nJT * nKT;
    float* sh_in = smem;          // 512
    float* red   = smem + 512;    // 8704
    for (int tile = blk; tile < ntiles; tile += NBLK) {
        int jt = tile % nJT, kt = tile / nJT;
        int j0 = jt << 6, k0 = kt << 6;
        // ---- stage inputs: sum NP partials (4-way striped) + premul + activation ----
        for (int i = 0; i < 2; ++i) {
            int f = i * 256 + t;
            int b = f >> 6, kk = f & 63;
            const float* src = in_parts + (size_t)b * K + k0 + kk;
            float v0 = 0.f, v1 = 0.f, v2 = 0.f, v3 = 0.f;
            int pp = 0;
            for (; pp + 4 <= NP; pp += 4) {
                v0 += ldv(src + (size_t)(pp + 0) * 8 * K);
                v1 += ldv(src + (size_t)(pp + 1) * 8 * K);
                v2 += ldv(src + (size_t)(pp + 2) * 8 * K);
                v3 += ldv(src + (size_t)(pp + 3) * 8 * K);
            }
            for (; pp < NP; ++pp) v0 += ldv(src + (size_t)pp * 8 * K);
            float v = ((v0 + v1) + (v2 + v3)) * premul;
            if (act == 1) {
                v = tanhf(v);
            } else if (act == 2) {
                v = v / (1.f + expf(-v));
            } else if (act == 3) {
                float th = vqc[(size_t)(k0 + kk) * 4 + 0] * 0.5f;
                float ph = vqc[(size_t)(k0 + kk) * 4 + 1];
                v *= (cosf(th) + sinf(th) * cosf(ph));
            }
            sh_in[b * 64 + kk] = v;
        }
        __syncthreads();
        // ---- compute: thread (kg=t>>4, jq=t&15): 4 k x 4 j x 8 b ----
        int jq = t & 15, kg = t >> 4;
        float acc[8][4];
#pragma unroll
        for (int b = 0; b < 8; ++b)
#pragma unroll
            for (int c = 0; c < 4; ++c) acc[b][c] = 0.f;
#pragma unroll
        for (int c2 = 0; c2 < 4; ++c2) {
            int kl = kg * 4 + c2;
            float4 w4 = *(const float4*)(W + (size_t)(k0 + kl) * Dout + j0 + jq * 4);
#pragma unroll
            for (int b = 0; b < 8; ++b) {
                float s = sh_in[b * 64 + kl];
                acc[b][0] += s * w4.x; acc[b][1] += s * w4.y;
                acc[b][2] += s * w4.z; acc[b][3] += s * w4.w;
            }
        }
        // ---- reduce 16 kg groups via LDS ----
#pragma unroll
        for (int b = 0; b < 8; ++b)
#pragma unroll
            for (int c = 0; c < 4; ++c)
                red[(b * 64 + jq * 4 + c) * 17 + kg] = acc[b][c];
        __syncthreads();
        for (int i = 0; i < 2; ++i) {
            int o = i * 256 + t;   // 0..511 = b*64 + jc
            float s = 0.f;
#pragma unroll
            for (int g = 0; g < 16; ++g) s += red[o * 17 + g];
            int b = o >> 6, jc = o & 63;
            int j = j0 + jc;
            if (bias != nullptr && kt == 0) s += bias[j];
            stv(&out_part[((size_t)kt * 8 + b) * Dout + j], s);
        }
        __syncthreads();
    }
}

__global__ __launch_bounds__(256) void fused_k(P p) {
    __shared__ float smem[9216];   // 36.9 KB
    int blk = blockIdx.x, t = threadIdx.x;
    float* ws = p.ws;
    int* bar = (int*)(ws + O_BAR);
    int ph = 0;

    // ===== phase A: x partial sums over S (256 blocks, 16 rows each) =====
    {
        int b = blk >> 5, c = blk & 31;
        const float4* x4 = (const float4*)p.x;
        size_t rbase = ((size_t)b * 512 + (size_t)c * 16) * 256;
        float4 a = make_float4(0.f, 0.f, 0.f, 0.f);
#pragma unroll
        for (int r = 0; r < 16; ++r) {
            float4 v = x4[rbase + (size_t)r * 256 + t];
            a.x += v.x; a.y += v.y; a.z += v.z; a.w += v.w;
        }
        float* dst = ws + O_XPA + ((size_t)c * 8 + b) * DDIM + (size_t)t * 4;
        stv(dst + 0, a.x); stv(dst + 1, a.y); stv(dst + 2, a.z); stv(dst + 3, a.w);
    }
    gbar(bar, ph++);

    const int DDm = DDIM * DDIM;
    float* y0p = ws + O_YP;
    float* h0p = ws + O_YP + 131072;
    float* h1p = ws + O_YP + 262144;

    mv_stage(blk, t, ws + O_XPA, 32, p.w_v, p.b_v, ws + O_VP, nullptr, 1.f / 512.f, 0, 1024, 1024, smem);
    gbar(bar, ph++);
    mv_stage(blk, t, ws + O_VP, 16, p.w_o, p.b_o, y0p, nullptr, 1.f, 0, 1024, 1024, smem);
    gbar(bar, ph++);
    // quantum layer 0
    mv_stage(blk, t, y0p, 16, p.aw1, p.ab1, ws + O_T0, nullptr, 1.f, 0, 1024, 1024, smem);
    gbar(bar, ph++);
    mv_stage(blk, t, ws + O_T0, 16, p.aw2, p.ab2, ws + O_A0, nullptr, 1.f, 1, 1024, 1024, smem);
    gbar(bar, ph++);
    mv_stage(blk, t, ws + O_A0, 16, p.pw1, p.pb1, ws + O_S0, p.vqc, 1.f, 3, 1024, 1024, smem);
    gbar(bar, ph++);
    mv_stage(blk, t, ws + O_S0, 16, p.pw2, p.pb2, h0p, nullptr, 1.f, 2, 1024, 1024, smem);
    gbar(bar, ph++);
    // quantum layer 1 (y = y0 + h0 -> NP=32 over yparts)
    mv_stage(blk, t, ws + O_YP, 32, p.aw1 + DDm, p.ab1 + 1024, ws + O_T0, nullptr, 1.f, 0, 1024, 1024, smem);
    gbar(bar, ph++);
    mv_stage(blk, t, ws + O_T0, 16, p.aw2 + DDm, p.ab2 + 1024, ws + O_A0, nullptr, 1.f, 1, 1024, 1024, smem);
    gbar(bar, ph++);
    mv_stage(blk, t, ws + O_A0, 16, p.pw1 + DDm, p.pb1 + 1024, ws + O_S0, p.vqc + 4096, 1.f, 3, 1024, 1024, smem);
    gbar(bar, ph++);
    mv_stage(blk, t, ws + O_S0, 16, p.pw2 + DDm, p.pb2 + 1024, h1p, nullptr, 1.f, 2, 1024, 1024, smem);
    gbar(bar, ph++);
    // macc = y @ mew1 + meb1  (y = y0+h0+h1 -> NP=48)
    mv_stage(blk, t, ws + O_YP, 48, p.mew1, p.meb1, ws + O_MP, nullptr, 1.f, 0, 1024, 1024, smem);
    gbar(bar, ph++);

    // ===== mem phase: mq, top-3, comb = [y, mem_ctx] (blocks 0..7) =====
    if (blk < 8) {
        float* sh_t  = smem;                 // 1024
        float* sh_p  = smem + 1024;          // 256
        float* sh_mq = smem + 1280;          // 16
        float* sh_sc = smem + 1296;          // 512
        float* sh_rv = smem + 1808;          // 256
        int*   sh_ri = (int*)(smem + 2064);  // 256
        float* sh_f1 = smem + 2320;          // 24
        float* sh_fb = smem + 2344;          // 8
        int*   sh_top= (int*)(smem + 2352);  // 3
        int b = blk;
        const float* mp = ws + O_MP;
        for (int i = t; i < DDIM; i += 256) {
            const float* sp = mp + (size_t)b * DDIM + i;
            float v0 = 0.f, v1 = 0.f, v2 = 0.f, v3 = 0.f;
            for (int q = 0; q < 16; q += 4) {
                v0 += ldv(sp + (size_t)(q + 0) * 8 * DDIM);
                v1 += ldv(sp + (size_t)(q + 1) * 8 * DDIM);
                v2 += ldv(sp + (size_t)(q + 2) * 8 * DDIM);
                v3 += ldv(sp + (size_t)(q + 3) * 8 * DDIM);
            }
            sh_t[i] = tanhf((v0 + v1) + (v2 + v3));
        }
        __syncthreads();
        {   // mq = tanh(macc) @ mew2 + meb2
            int j = t & 15, g = t >> 4;
            float s = 0.f;
            int kbase = g * 64;
            for (int k = 0; k < 64; ++k) s += sh_t[kbase + k] * p.mew2[(size_t)(kbase + k) * 16 + j];
            sh_p[t] = s;
        }
        __syncthreads();
        if (t < 16) {
            float v = 0.f;
            for (int g = 0; g < 16; ++g) v += sh_p[g * 16 + t];
            sh_mq[t] = v + p.meb2[t];
        }
        __syncthreads();
        for (int m = t; m < 512; m += 256) {
            float d = 0.f;
#pragma unroll
            for (int i = 0; i < 16; ++i) d += sh_mq[i] * p.mst[m * 16 + i];
            sh_sc[m] = d * d;
        }
        __syncthreads();
        for (int r = 0; r < 3; ++r) {
            float bv = -1.f; int bi = -1;
            for (int m = t; m < 512; m += 256) {
                float v = sh_sc[m];
                if (v > bv || (v == bv && m > bi)) { bv = v; bi = m; }
            }
            sh_rv[t] = bv; sh_ri[t] = bi;
            __syncthreads();
            for (int st = 128; st > 0; st >>= 1) {
                if (t < st) {
                    float v2 = sh_rv[t + st]; int i2 = sh_ri[t + st];
                    if (v2 > sh_rv[t] || (v2 == sh_rv[t] && i2 > sh_ri[t])) { sh_rv[t] = v2; sh_ri[t] = i2; }
                }
                __syncthreads();
            }
            if (t == 0) { sh_top[r] = sh_ri[0]; sh_sc[sh_ri[0]] = -1.f; }
            __syncthreads();
        }
        if (t < 24) {
            int k = t >> 3, i = t & 7;
            int m = sh_top[k];
            float a = p.rb1[i];
#pragma unroll
            for (int ii = 0; ii < 8; ++ii) a += p.mst[m * 16 + ii] * p.rw1[ii * 8 + i];
            sh_f1[k * 8 + i] = tanhf(a);
        }
        __syncthreads();
        if (t < 8) sh_fb[t] = (sh_f1[t] + sh_f1[8 + t] + sh_f1[16 + t]) * (1.f / 3.f);
        __syncthreads();
        float* comb = ws + O_COMB;
        const float* yp = ws + O_YP;
        for (int jj = t; jj < DDIM; jj += 256) {
            float v = p.rb2[jj];
#pragma unroll
            for (int i = 0; i < 8; ++i) v += sh_fb[i] * p.rw2[(size_t)i * DDIM + jj];
            stv(&comb[(size_t)b * 2048 + 1024 + jj], v);
            const float* sp = yp + (size_t)b * DDIM + jj;
            float v0 = 0.f, v1 = 0.f, v2 = 0.f, v3 = 0.f;
            for (int q = 0; q < 48; q += 4) {
                v0 += ldv(sp + (size_t)(q + 0) * 8 * DDIM);
                v1 += ldv(sp + (size_t)(q + 1) * 8 * DDIM);
                v2 += ldv(sp + (size_t)(q + 2) * 8 * DDIM);
                v3 += ldv(sp + (size_t)(q + 3) * 8 * DDIM);
            }
            stv(&comb[(size_t)b * 2048 + jj], (v0 + v1) + (v2 + v3));
        }
    }
    gbar(bar, ph++);

    // bridge MLP
    mv_stage(blk, t, ws + O_COMB, 1, p.brw1, p.brb1, ws + O_HBA, nullptr, 1.f, 0, 2048, 2048, smem);
    gbar(bar, ph++);
    mv_stage(blk, t, ws + O_HBA, 32, p.brw2, p.brb2, ws + O_HBP, nullptr, 1.f, 2, 2048, 1024, smem);
    gbar(bar, ph++);

    // ===== layernorm (blocks 0..7) =====
    if (blk < 8) {
        float* sh_v = smem;          // 1024
        float* rs   = smem + 1024;   // 256
        float* rq   = smem + 1280;   // 256
        int b = blk;
        const float* hbp = ws + O_HBP;
        float s = 0.f, q = 0.f;
        for (int i = t; i < DDIM; i += 256) {
            const float* sp = hbp + (size_t)b * DDIM + i;
            float v0 = 0.f, v1 = 0.f, v2 = 0.f, v3 = 0.f;
            for (int pp = 0; pp < 32; pp += 4) {
                v0 += ldv(sp + (size_t)(pp + 0) * 8 * DDIM);
                v1 += ldv(sp + (size_t)(pp + 1) * 8 * DDIM);
                v2 += ldv(sp + (size_t)(pp + 2) * 8 * DDIM);
                v3 += ldv(sp + (size_t)(pp + 3) * 8 * DDIM);
            }
            float v = (v0 + v1) + (v2 + v3);
            sh_v[i] = v;
            s += v; q += v * v;
        }
        rs[t] = s; rq[t] = q;
        __syncthreads();
        for (int st = 128; st > 0; st >>= 1) {
            if (t < st) { rs[t] += rs[t + st]; rq[t] += rq[t + st]; }
            __syncthreads();
        }
        float mu  = rs[0] * (1.f / DDIM);
        float var = rq[0] * (1.f / DDIM) - mu * mu;
        var = var < 0.f ? 0.f : var;
        float inv = 1.f / sqrtf(var + 1e-5f);
        for (int i = t; i < DDIM; i += 256) {
            float v = sh_v[i];
            stv(&(ws + O_ROW)[(size_t)b * DDIM + i], (v - mu) * inv * p.lnsc[i] + p.lnof[i]);
        }
    }
    gbar(bar, ph++);

    // ===== broadcast: block=(b, s-chunk of 16), row staged via LDS, float4 out =====
    {
        int b = blk >> 5, c = blk & 31;
        float* sh_row = smem;   // 1024 floats
        const float* rp = ws + O_ROW + (size_t)b * DDIM;
#pragma unroll
        for (int i = 0; i < 4; ++i) sh_row[t * 4 + i] = ldv(rp + t * 4 + i);
        __syncthreads();
        float4 rv = ((const float4*)sh_row)[t];
        float4* out4 = (float4*)p.out;
        size_t base = ((size_t)b * 512 + (size_t)c * 16) * 256;
#pragma unroll
        for (int r = 0; r < 16; ++r)
            out4[base + (size_t)r * 256 + t] = rv;
    }
}

extern "C" void kernel_launch(void* const* d_in, const int* in_sizes, int n_in,
                              void* d_out, int out_size, void* d_ws, size_t ws_size,
                              hipStream_t stream) {
    P hp;
    hp.x    = (const float*)d_in[0];
    hp.w_v  = (const float*)d_in[5];
    hp.b_v  = (const float*)d_in[6];
    hp.w_o  = (const float*)d_in[7];
    hp.b_o  = (const float*)d_in[8];
    hp.aw1  = (const float*)d_in[15];
    hp.ab1  = (const float*)d_in[16];
    hp.aw2  = (const float*)d_in[17];
    hp.ab2  = (const float*)d_in[18];
    hp.vqc  = (const float*)d_in[19];
    hp.pw1  = (const float*)d_in[20];
    hp.pb1  = (const float*)d_in[21];
    hp.pw2  = (const float*)d_in[22];
    hp.pb2  = (const float*)d_in[23];
    hp.mew1 = (const float*)d_in[24];
    hp.meb1 = (const float*)d_in[25];
    hp.mew2 = (const float*)d_in[26];
    hp.meb2 = (const float*)d_in[27];
    hp.mst  = (const float*)d_in[28];
    hp.rw1  = (const float*)d_in[29];
    hp.rb1  = (const float*)d_in[30];
    hp.rw2  = (const float*)d_in[31];
    hp.rb2  = (const float*)d_in[32];
    hp.brw1 = (const float*)d_in[33];
    hp.brb1 = (const float*)d_in[34];
    hp.brw2 = (const float*)d_in[35];
    hp.brb2 = (const float*)d_in[36];
    hp.lnsc = (const float*)d_in[37];
    hp.lnof = (const float*)d_in[38];
    hp.ws   = (float*)d_ws;
    hp.out  = (float*)d_out;

    // zero barrier region: arrive[16][16][32] + release[256][32] ints
    hipMemsetAsync((char*)d_ws + (size_t)O_BAR * 4, 0,
                   (size_t)(NPH * 16 * 32 + NBLK * 32) * sizeof(int), stream);

    fused_k<<<NBLK, 256, 0, stream>>>(hp);
}

// Round 7
// 348.671 us; speedup vs baseline: 1.9401x; 1.9401x over previous
//
#include <hip/hip_runtime.h>
#include <math.h>

#define DDIM 1024

// ---- workspace layout (float offsets) ----
#define O_XPA   0          // [32][8][1024]  262144
#define O_VP    327680     // [16][8][1024]  131072
#define O_YP    458752     // [48][8][1024]  393216  (y0 | h0 | h1)
#define O_T0    851968     // [16][8][1024]  131072
#define O_A0    983040     // [16][8][1024]  131072
#define O_S0    1114112    // [16][8][1024]  131072
#define O_MP    1245184    // [16][8][1024]  131072
#define O_COMB  1376256    // [8][2048]       16384
#define O_HBA   1392640    // [32][8][2048]  524288
#define O_HBP   1916928    // [32][8][1024]  262144
#define O_ROW   2179072    // [8][1024]        8192
#define O_BAR   2187264    // barrier region: arrive[16][16][32] + release[256][32] ints

#define NBLK 256
#define NPH  16

struct P {
    const float *x, *w_v, *b_v, *w_o, *b_o, *aw1, *ab1, *aw2, *ab2, *vqc,
                *pw1, *pb1, *pw2, *pb2, *mew1, *meb1, *mew2, *meb2, *mst,
                *rw1, *rb1, *rw2, *rb2, *brw1, *brb1, *brw2, *brb2, *lnsc, *lnof;
    float *ws;
    float *out;
};

// ---- LLC-resident (L2-bypassing) accessors for inter-phase data ----
__device__ __forceinline__ float ldv(const float* p) {
    return __hip_atomic_load(p, __ATOMIC_RELAXED, __HIP_MEMORY_SCOPE_AGENT);
}
__device__ __forceinline__ void stv(float* p, float v) {
    __hip_atomic_store(p, v, __ATOMIC_RELAXED, __HIP_MEMORY_SCOPE_AGENT);
}

// ---- grid barrier v3: NO acquire-polling (no per-iteration cache invalidates) ----
// arrive: [NPH][16 groups][32-int stride]; release: [NBLK][32-int stride].
// Release semantics: ONE agent-scope release fence per block before relaxed arrival
// (drains write-through stv stores to LLC). Polls are RELAXED (plain LLC reads).
// After poll exit: workgroup-scope acquire fence (compiler ordering only — all
// cross-phase data is read via agent-scope LLC loads, so no stale L1/L2 hazard).
__device__ __forceinline__ void gbar(int* __restrict__ bar, int ph) {
    int blk = blockIdx.x, t = threadIdx.x;
    int* arrive  = bar;                   // NPH*16*32 ints
    int* release = bar + NPH * 16 * 32;   // NBLK*32 ints
    __syncthreads();
    if (blk == 0) {
        if (t == 0) {
            __builtin_amdgcn_fence(__ATOMIC_RELEASE, "agent");
            __hip_atomic_fetch_add(&arrive[(ph * 16 + 0) * 32], 1,
                                   __ATOMIC_RELAXED, __HIP_MEMORY_SCOPE_AGENT);
        }
        if (t < 16) {
            const int* cnt = &arrive[(ph * 16 + t) * 32];
            while (__hip_atomic_load(cnt, __ATOMIC_RELAXED, __HIP_MEMORY_SCOPE_AGENT) < 16)
                __builtin_amdgcn_s_sleep(4);
        }
        __syncthreads();
        // arrivals confirmed in LLC -> publish per-block release flags (relaxed)
        __hip_atomic_store(&release[t * 32], ph + 1,
                           __ATOMIC_RELAXED, __HIP_MEMORY_SCOPE_AGENT);
    } else {
        if (t == 0) {
            __builtin_amdgcn_fence(__ATOMIC_RELEASE, "agent");
            __hip_atomic_fetch_add(&arrive[(ph * 16 + (blk >> 4)) * 32], 1,
                                   __ATOMIC_RELAXED, __HIP_MEMORY_SCOPE_AGENT);
            while (__hip_atomic_load(&release[blk * 32], __ATOMIC_RELAXED,
                                     __HIP_MEMORY_SCOPE_AGENT) < ph + 1)
                __builtin_amdgcn_s_sleep(4);
        }
        __syncthreads();
    }
    __builtin_amdgcn_fence(__ATOMIC_ACQUIRE, "workgroup");
    __syncthreads();
}

// Generic batch-8 vec-mat stage, 64x64 tiles, grid-stride. SINGLE code copy (noinline).
// in_parts: [NP][8][K] (summed at staging via LLC loads); out_part: [nKT][8][Dout] (LLC stores).
// act: 0=id 1=tanh 2=silu 3=*quantum-scale(vqc). Bias added on kt==0.
__device__ __attribute__((noinline)) void mv_stage(int blk, int t,
        const float* __restrict__ in_parts, int NP,
        const float* __restrict__ W, const float* __restrict__ bias,
        float* __restrict__ out_part, const float* __restrict__ vqc,
        float premul, int act, int K, int Dout, float* smem) {
    int nJT = Dout >> 6, nKT = K >> 6;
    int ntiles = nJT * nKT;
    float* sh_in = smem;          // 512
    float* red   = smem + 512;    // 8704
    for (int tile = blk; tile < ntiles; tile += NBLK) {
        int jt = tile % nJT, kt = tile / nJT;
        int j0 = jt << 6, k0 = kt << 6;
        // ---- stage inputs: sum NP partials (4-way striped) + premul + activation ----
        for (int i = 0; i < 2; ++i) {
            int f = i * 256 + t;
            int b = f >> 6, kk = f & 63;
            const float* src = in_parts + (size_t)b * K + k0 + kk;
            float v0 = 0.f, v1 = 0.f, v2 = 0.f, v3 = 0.f;
            int pp = 0;
            for (; pp + 4 <= NP; pp += 4) {
                v0 += ldv(src + (size_t)(pp + 0) * 8 * K);
                v1 += ldv(src + (size_t)(pp + 1) * 8 * K);
                v2 += ldv(src + (size_t)(pp + 2) * 8 * K);
                v3 += ldv(src + (size_t)(pp + 3) * 8 * K);
            }
            for (; pp < NP; ++pp) v0 += ldv(src + (size_t)pp * 8 * K);
            float v = ((v0 + v1) + (v2 + v3)) * premul;
            if (act == 1) {
                v = tanhf(v);
            } else if (act == 2) {
                v = v / (1.f + expf(-v));
            } else if (act == 3) {
                float th = vqc[(size_t)(k0 + kk) * 4 + 0] * 0.5f;
                float ph = vqc[(size_t)(k0 + kk) * 4 + 1];
                v *= (cosf(th) + sinf(th) * cosf(ph));
            }
            sh_in[b * 64 + kk] = v;
        }
        __syncthreads();
        // ---- compute: thread (kg=t>>4, jq=t&15): 4 k x 4 j x 8 b ----
        int jq = t & 15, kg = t >> 4;
        float acc[8][4];
#pragma unroll
        for (int b = 0; b < 8; ++b)
#pragma unroll
            for (int c = 0; c < 4; ++c) acc[b][c] = 0.f;
#pragma unroll
        for (int c2 = 0; c2 < 4; ++c2) {
            int kl = kg * 4 + c2;
            float4 w4 = *(const float4*)(W + (size_t)(k0 + kl) * Dout + j0 + jq * 4);
#pragma unroll
            for (int b = 0; b < 8; ++b) {
                float s = sh_in[b * 64 + kl];
                acc[b][0] += s * w4.x; acc[b][1] += s * w4.y;
                acc[b][2] += s * w4.z; acc[b][3] += s * w4.w;
            }
        }
        // ---- reduce 16 kg groups via LDS ----
#pragma unroll
        for (int b = 0; b < 8; ++b)
#pragma unroll
            for (int c = 0; c < 4; ++c)
                red[(b * 64 + jq * 4 + c) * 17 + kg] = acc[b][c];
        __syncthreads();
        for (int i = 0; i < 2; ++i) {
            int o = i * 256 + t;   // 0..511 = b*64 + jc
            float s = 0.f;
#pragma unroll
            for (int g = 0; g < 16; ++g) s += red[o * 17 + g];
            int b = o >> 6, jc = o & 63;
            int j = j0 + jc;
            if (bias != nullptr && kt == 0) s += bias[j];
            stv(&out_part[((size_t)kt * 8 + b) * Dout + j], s);
        }
        __syncthreads();
    }
}

__global__ __launch_bounds__(256) void fused_k(P p) {
    __shared__ float smem[9216];   // 36.9 KB
    int blk = blockIdx.x, t = threadIdx.x;
    float* ws = p.ws;
    int* bar = (int*)(ws + O_BAR);
    int ph = 0;

    // ===== phase A: x partial sums over S (256 blocks, 16 rows each) =====
    {
        int b = blk >> 5, c = blk & 31;
        const float4* x4 = (const float4*)p.x;
        size_t rbase = ((size_t)b * 512 + (size_t)c * 16) * 256;
        float4 a = make_float4(0.f, 0.f, 0.f, 0.f);
#pragma unroll
        for (int r = 0; r < 16; ++r) {
            float4 v = x4[rbase + (size_t)r * 256 + t];
            a.x += v.x; a.y += v.y; a.z += v.z; a.w += v.w;
        }
        float* dst = ws + O_XPA + ((size_t)c * 8 + b) * DDIM + (size_t)t * 4;
        stv(dst + 0, a.x); stv(dst + 1, a.y); stv(dst + 2, a.z); stv(dst + 3, a.w);
    }
    gbar(bar, ph++);

    const int DDm = DDIM * DDIM;
    float* y0p = ws + O_YP;
    float* h0p = ws + O_YP + 131072;
    float* h1p = ws + O_YP + 262144;

    mv_stage(blk, t, ws + O_XPA, 32, p.w_v, p.b_v, ws + O_VP, nullptr, 1.f / 512.f, 0, 1024, 1024, smem);
    gbar(bar, ph++);
    mv_stage(blk, t, ws + O_VP, 16, p.w_o, p.b_o, y0p, nullptr, 1.f, 0, 1024, 1024, smem);
    gbar(bar, ph++);
    // quantum layer 0
    mv_stage(blk, t, y0p, 16, p.aw1, p.ab1, ws + O_T0, nullptr, 1.f, 0, 1024, 1024, smem);
    gbar(bar, ph++);
    mv_stage(blk, t, ws + O_T0, 16, p.aw2, p.ab2, ws + O_A0, nullptr, 1.f, 1, 1024, 1024, smem);
    gbar(bar, ph++);
    mv_stage(blk, t, ws + O_A0, 16, p.pw1, p.pb1, ws + O_S0, p.vqc, 1.f, 3, 1024, 1024, smem);
    gbar(bar, ph++);
    mv_stage(blk, t, ws + O_S0, 16, p.pw2, p.pb2, h0p, nullptr, 1.f, 2, 1024, 1024, smem);
    gbar(bar, ph++);
    // quantum layer 1 (y = y0 + h0 -> NP=32 over yparts)
    mv_stage(blk, t, ws + O_YP, 32, p.aw1 + DDm, p.ab1 + 1024, ws + O_T0, nullptr, 1.f, 0, 1024, 1024, smem);
    gbar(bar, ph++);
    mv_stage(blk, t, ws + O_T0, 16, p.aw2 + DDm, p.ab2 + 1024, ws + O_A0, nullptr, 1.f, 1, 1024, 1024, smem);
    gbar(bar, ph++);
    mv_stage(blk, t, ws + O_A0, 16, p.pw1 + DDm, p.pb1 + 1024, ws + O_S0, p.vqc + 4096, 1.f, 3, 1024, 1024, smem);
    gbar(bar, ph++);
    mv_stage(blk, t, ws + O_S0, 16, p.pw2 + DDm, p.pb2 + 1024, h1p, nullptr, 1.f, 2, 1024, 1024, smem);
    gbar(bar, ph++);
    // macc = y @ mew1 + meb1  (y = y0+h0+h1 -> NP=48)
    mv_stage(blk, t, ws + O_YP, 48, p.mew1, p.meb1, ws + O_MP, nullptr, 1.f, 0, 1024, 1024, smem);
    gbar(bar, ph++);

    // ===== mem phase: mq, top-3, comb = [y, mem_ctx] (blocks 0..7) =====
    if (blk < 8) {
        float* sh_t  = smem;                 // 1024
        float* sh_p  = smem + 1024;          // 256
        float* sh_mq = smem + 1280;          // 16
        float* sh_sc = smem + 1296;          // 512
        float* sh_rv = smem + 1808;          // 256
        int*   sh_ri = (int*)(smem + 2064);  // 256
        float* sh_f1 = smem + 2320;          // 24
        float* sh_fb = smem + 2344;          // 8
        int*   sh_top= (int*)(smem + 2352);  // 3
        int b = blk;
        const float* mp = ws + O_MP;
        for (int i = t; i < DDIM; i += 256) {
            const float* sp = mp + (size_t)b * DDIM + i;
            float v0 = 0.f, v1 = 0.f, v2 = 0.f, v3 = 0.f;
            for (int q = 0; q < 16; q += 4) {
                v0 += ldv(sp + (size_t)(q + 0) * 8 * DDIM);
                v1 += ldv(sp + (size_t)(q + 1) * 8 * DDIM);
                v2 += ldv(sp + (size_t)(q + 2) * 8 * DDIM);
                v3 += ldv(sp + (size_t)(q + 3) * 8 * DDIM);
            }
            sh_t[i] = tanhf((v0 + v1) + (v2 + v3));
        }
        __syncthreads();
        {   // mq = tanh(macc) @ mew2 + meb2
            int j = t & 15, g = t >> 4;
            float s = 0.f;
            int kbase = g * 64;
            for (int k = 0; k < 64; ++k) s += sh_t[kbase + k] * p.mew2[(size_t)(kbase + k) * 16 + j];
            sh_p[t] = s;
        }
        __syncthreads();
        if (t < 16) {
            float v = 0.f;
            for (int g = 0; g < 16; ++g) v += sh_p[g * 16 + t];
            sh_mq[t] = v + p.meb2[t];
        }
        __syncthreads();
        for (int m = t; m < 512; m += 256) {
            float d = 0.f;
#pragma unroll
            for (int i = 0; i < 16; ++i) d += sh_mq[i] * p.mst[m * 16 + i];
            sh_sc[m] = d * d;
        }
        __syncthreads();
        for (int r = 0; r < 3; ++r) {
            float bv = -1.f; int bi = -1;
            for (int m = t; m < 512; m += 256) {
                float v = sh_sc[m];
                if (v > bv || (v == bv && m > bi)) { bv = v; bi = m; }
            }
            sh_rv[t] = bv; sh_ri[t] = bi;
            __syncthreads();
            for (int st = 128; st > 0; st >>= 1) {
                if (t < st) {
                    float v2 = sh_rv[t + st]; int i2 = sh_ri[t + st];
                    if (v2 > sh_rv[t] || (v2 == sh_rv[t] && i2 > sh_ri[t])) { sh_rv[t] = v2; sh_ri[t] = i2; }
                }
                __syncthreads();
            }
            if (t == 0) { sh_top[r] = sh_ri[0]; sh_sc[sh_ri[0]] = -1.f; }
            __syncthreads();
        }
        if (t < 24) {
            int k = t >> 3, i = t & 7;
            int m = sh_top[k];
            float a = p.rb1[i];
#pragma unroll
            for (int ii = 0; ii < 8; ++ii) a += p.mst[m * 16 + ii] * p.rw1[ii * 8 + i];
            sh_f1[k * 8 + i] = tanhf(a);
        }
        __syncthreads();
        if (t < 8) sh_fb[t] = (sh_f1[t] + sh_f1[8 + t] + sh_f1[16 + t]) * (1.f / 3.f);
        __syncthreads();
        float* comb = ws + O_COMB;
        const float* yp = ws + O_YP;
        for (int jj = t; jj < DDIM; jj += 256) {
            float v = p.rb2[jj];
#pragma unroll
            for (int i = 0; i < 8; ++i) v += sh_fb[i] * p.rw2[(size_t)i * DDIM + jj];
            stv(&comb[(size_t)b * 2048 + 1024 + jj], v);
            const float* sp = yp + (size_t)b * DDIM + jj;
            float v0 = 0.f, v1 = 0.f, v2 = 0.f, v3 = 0.f;
            for (int q = 0; q < 48; q += 4) {
                v0 += ldv(sp + (size_t)(q + 0) * 8 * DDIM);
                v1 += ldv(sp + (size_t)(q + 1) * 8 * DDIM);
                v2 += ldv(sp + (size_t)(q + 2) * 8 * DDIM);
                v3 += ldv(sp + (size_t)(q + 3) * 8 * DDIM);
            }
            stv(&comb[(size_t)b * 2048 + jj], (v0 + v1) + (v2 + v3));
        }
    }
    gbar(bar, ph++);

    // bridge MLP
    mv_stage(blk, t, ws + O_COMB, 1, p.brw1, p.brb1, ws + O_HBA, nullptr, 1.f, 0, 2048, 2048, smem);
    gbar(bar, ph++);
    mv_stage(blk, t, ws + O_HBA, 32, p.brw2, p.brb2, ws + O_HBP, nullptr, 1.f, 2, 2048, 1024, smem);
    gbar(bar, ph++);

    // ===== layernorm (blocks 0..7) =====
    if (blk < 8) {
        float* sh_v = smem;          // 1024
        float* rs   = smem + 1024;   // 256
        float* rq   = smem + 1280;   // 256
        int b = blk;
        const float* hbp = ws + O_HBP;
        float s = 0.f, q = 0.f;
        for (int i = t; i < DDIM; i += 256) {
            const float* sp = hbp + (size_t)b * DDIM + i;
            float v0 = 0.f, v1 = 0.f, v2 = 0.f, v3 = 0.f;
            for (int pp = 0; pp < 32; pp += 4) {
                v0 += ldv(sp + (size_t)(pp + 0) * 8 * DDIM);
                v1 += ldv(sp + (size_t)(pp + 1) * 8 * DDIM);
                v2 += ldv(sp + (size_t)(pp + 2) * 8 * DDIM);
                v3 += ldv(sp + (size_t)(pp + 3) * 8 * DDIM);
            }
            float v = (v0 + v1) + (v2 + v3);
            sh_v[i] = v;
            s += v; q += v * v;
        }
        rs[t] = s; rq[t] = q;
        __syncthreads();
        for (int st = 128; st > 0; st >>= 1) {
            if (t < st) { rs[t] += rs[t + st]; rq[t] += rq[t + st]; }
            __syncthreads();
        }
        float mu  = rs[0] * (1.f / DDIM);
        float var = rq[0] * (1.f / DDIM) - mu * mu;
        var = var < 0.f ? 0.f : var;
        float inv = 1.f / sqrtf(var + 1e-5f);
        for (int i = t; i < DDIM; i += 256) {
            float v = sh_v[i];
            stv(&(ws + O_ROW)[(size_t)b * DDIM + i], (v - mu) * inv * p.lnsc[i] + p.lnof[i]);
        }
    }
    gbar(bar, ph++);

    // ===== broadcast: block=(b, s-chunk of 16), row staged via LDS, float4 out =====
    {
        int b = blk >> 5, c = blk & 31;
        float* sh_row = smem;   // 1024 floats
        const float* rp = ws + O_ROW + (size_t)b * DDIM;
#pragma unroll
        for (int i = 0; i < 4; ++i) sh_row[t * 4 + i] = ldv(rp + t * 4 + i);
        __syncthreads();
        float4 rv = ((const float4*)sh_row)[t];
        float4* out4 = (float4*)p.out;
        size_t base = ((size_t)b * 512 + (size_t)c * 16) * 256;
#pragma unroll
        for (int r = 0; r < 16; ++r)
            out4[base + (size_t)r * 256 + t] = rv;
    }
}

extern "C" void kernel_launch(void* const* d_in, const int* in_sizes, int n_in,
                              void* d_out, int out_size, void* d_ws, size_t ws_size,
                              hipStream_t stream) {
    P hp;
    hp.x    = (const float*)d_in[0];
    hp.w_v  = (const float*)d_in[5];
    hp.b_v  = (const float*)d_in[6];
    hp.w_o  = (const float*)d_in[7];
    hp.b_o  = (const float*)d_in[8];
    hp.aw1  = (const float*)d_in[15];
    hp.ab1  = (const float*)d_in[16];
    hp.aw2  = (const float*)d_in[17];
    hp.ab2  = (const float*)d_in[18];
    hp.vqc  = (const float*)d_in[19];
    hp.pw1  = (const float*)d_in[20];
    hp.pb1  = (const float*)d_in[21];
    hp.pw2  = (const float*)d_in[22];
    hp.pb2  = (const float*)d_in[23];
    hp.mew1 = (const float*)d_in[24];
    hp.meb1 = (const float*)d_in[25];
    hp.mew2 = (const float*)d_in[26];
    hp.meb2 = (const float*)d_in[27];
    hp.mst  = (const float*)d_in[28];
    hp.rw1  = (const float*)d_in[29];
    hp.rb1  = (const float*)d_in[30];
    hp.rw2  = (const float*)d_in[31];
    hp.rb2  = (const float*)d_in[32];
    hp.brw1 = (const float*)d_in[33];
    hp.brb1 = (const float*)d_in[34];
    hp.brw2 = (const float*)d_in[35];
    hp.brb2 = (const float*)d_in[36];
    hp.lnsc = (const float*)d_in[37];
    hp.lnof = (const float*)d_in[38];
    hp.ws   = (float*)d_ws;
    hp.out  = (float*)d_out;

    // zero barrier region: arrive[16][16][32] + release[256][32] ints
    hipMemsetAsync((char*)d_ws + (size_t)O_BAR * 4, 0,
                   (size_t)(NPH * 16 * 32 + NBLK * 32) * sizeof(int), stream);

    fused_k<<<NBLK, 256, 0, stream>>>(hp);
}